// Round 4
// baseline (239.966 us; speedup 1.0000x reference)
//
#include <hip/hip_runtime.h>
#include <hip/hip_cooperative_groups.h>
#include <math.h>

namespace cg = cooperative_groups;

// Problem geometry (fixed by setup_inputs): N=64, C=128, H=W=56
#define NBATCH 64
#define NCHAN  128
#define HWSZ   3136          // 56*56
#define HW4    784           // HWSZ/4
#define NHW    200704        // NBATCH*HWSZ (elements per channel)
#define NBLK   1024          // 4 blocks/CU on 256 CUs -> cooperative-safe
#define SLICES_PER_BLK 8     // 8192 slices / 1024 blocks

constexpr float EPS_  = 1e-5f;
constexpr float MOM_  = 0.1f;

typedef float f32x4 __attribute__((ext_vector_type(4)));  // native vec for NT store

// AP2(x) = sign(x) * 2^round(log2|x|), round-half-to-even (matches jnp.round).
// Empirically bit-matched vs np reference (round 1/3 absmax ~3e-5) — do not change.
__device__ __forceinline__ float ap2_precise(float v) {
    float a = fabsf(v);
    float p = exp2f(rintf(log2f(a)));   // log2f(0) = -inf -> exp2f(-inf) = 0
    return copysignf(p, v);
}

// Wave-wide (64-lane) sum; result broadcast to all lanes. Deterministic tree.
__device__ __forceinline__ float wave_sum_bcast(float v) {
    #pragma unroll
    for (int off = 32; off > 0; off >>= 1) v += __shfl_down(v, off, 64);
    return __shfl(v, 0, 64);
}

__global__ void __launch_bounds__(256, 4)
fused_shiftnorm(const float* __restrict__ x,
                const float* __restrict__ weight,
                const float* __restrict__ bias,
                const float* __restrict__ rmean,
                const float* __restrict__ rvar,
                float* __restrict__ out,
                float* __restrict__ part_mean,
                float* __restrict__ part_var) {
    cg::grid_group grid = cg::this_grid();
    const int lane = threadIdx.x & 63;
    const int w    = threadIdx.x >> 6;          // wave id 0..3
    const int base = blockIdx.x * SLICES_PER_BLK;

    // ---------- Phase 1: per-(n,c)-slice sum of x ----------
    #pragma unroll
    for (int k = 0; k < SLICES_PER_BLK; k += 4) {
        const int s = base + k + w;             // wave w owns slice k+w
        const float4* xp = (const float4*)(x + (size_t)s * HWSZ);
        float acc = 0.f;
        for (int i = lane; i < HW4; i += 64) {
            float4 v = xp[i];
            acc += (v.x + v.y) + (v.z + v.w);
        }
        const float tot = wave_sum_bcast(acc);
        if (lane == 0) {
            const int n = s >> 7, c = s & 127;
            part_mean[c * NBATCH + n] = tot;
        }
    }
    grid.sync();

    // ---------- Phase 2: per-slice sum of centered*AP2(centered) ----------
    #pragma unroll
    for (int k = 0; k < SLICES_PER_BLK; k += 4) {
        const int s = base + k + w;
        const int n = s >> 7, c = s & 127;
        const float msum = wave_sum_bcast(part_mean[c * NBATCH + lane]);
        const float m = (1.f - MOM_) * rmean[c] + MOM_ * (msum / (float)NHW);
        const float4* xp = (const float4*)(x + (size_t)s * HWSZ);
        float acc = 0.f;
        for (int i = lane; i < HW4; i += 64) {
            float4 v = xp[i];
            float c0 = v.x - m, c1 = v.y - m, c2 = v.z - m, c3 = v.w - m;
            acc += c0 * ap2_precise(c0);
            acc += c1 * ap2_precise(c1);
            acc += c2 * ap2_precise(c2);
            acc += c3 * ap2_precise(c3);
        }
        const float tot = wave_sum_bcast(acc);
        if (lane == 0) part_var[c * NBATCH + n] = tot;
    }
    grid.sync();

    // ---------- Phase 3: out = AP2(w)*inv_std*(x - rm) + bias ----------
    #pragma unroll
    for (int k = 0; k < SLICES_PER_BLK; k += 4) {
        const int s = base + k + w;
        const int c = s & 127;
        const float msum = wave_sum_bcast(part_mean[c * NBATCH + lane]);
        const float vsum = wave_sum_bcast(part_var[c * NBATCH + lane]);
        const float m  = (1.f - MOM_) * rmean[c] + MOM_ * (msum / (float)NHW);
        const float rv = (1.f - MOM_) * rvar[c]  + MOM_ * (vsum / (float)NHW);
        const float inv_std = ap2_precise(1.0f / sqrtf(rv + EPS_));
        const float sc = ap2_precise(weight[c]) * inv_std;  // powers of 2: exact
        const float bb = bias[c];
        const float4* xp = (const float4*)(x + (size_t)s * HWSZ);
        f32x4* op = (f32x4*)(out + (size_t)s * HWSZ);
        for (int i = lane; i < HW4; i += 64) {
            float4 v = xp[i];
            f32x4 o;
            o.x = fmaf(sc, v.x - m, bb);
            o.y = fmaf(sc, v.y - m, bb);
            o.z = fmaf(sc, v.z - m, bb);
            o.w = fmaf(sc, v.w - m, bb);
            __builtin_nontemporal_store(o, &op[i]);
        }
    }
}

extern "C" void kernel_launch(void* const* d_in, const int* in_sizes, int n_in,
                              void* d_out, int out_size, void* d_ws, size_t ws_size,
                              hipStream_t stream) {
    const float* x      = (const float*)d_in[0];
    const float* weight = (const float*)d_in[1];
    const float* bias   = (const float*)d_in[2];
    const float* rmean  = (const float*)d_in[3];
    const float* rvar   = (const float*)d_in[4];
    float* out = (float*)d_out;

    float* ws        = (float*)d_ws;
    float* part_mean = ws;                 // 8192 floats
    float* part_var  = ws + 8192;          // 8192 floats

    void* args[] = {(void*)&x, (void*)&weight, (void*)&bias, (void*)&rmean,
                    (void*)&rvar, (void*)&out, (void*)&part_mean, (void*)&part_var};
    hipLaunchCooperativeKernel(reinterpret_cast<void*>(fused_shiftnorm),
                               dim3(NBLK), dim3(256), args, 0, stream);
}